// Round 5
// baseline (27912.976 us; speedup 1.0000x reference)
//
#include <hip/hip_runtime.h>
#include <math.h>

// ---------------------------------------------------------------------------
// FISTA sparse solver, L=128, D=512, M=2048, MAX_ITER=200, EPS=1e-5.
// R5: fence-free coherence model.
//  - R4 bottleneck: per-barrier __threadfence (acquire) invalidated ALL of L2
//    -> x/mask/py refetched cold every half-iteration (7MB/iter @ 25-58GB/s,
//    latency-bound, VALUBusy 11%).
//  - R5: NO cache-wide fences. Immutable arrays (x,mask,py,DtD,ctab) = plain
//    loads, permanently L2-hot. Mutable cross-block arrays (R, A, AX, PART,
//    done) = __hip_atomic_* RELAXED/AGENT per-access (device-coherent at the
//    IC point; no stale-copy hazard by construction). Block-private (BM,
//    YPREV) = plain. Barrier: RELEASE arrival (waitcnt+wbl2, NO invalidate),
//    relaxed polls, compiler barrier after wake.
//  - Occupancy: 512 blocks x 512 thr, __launch_bounds__(512,4) => 2 blocks/CU
//    guaranteed co-resident (16 waves/CU).
// Phase math, conv check, early-exit semantics identical to R2-R4 (passed 4x).
// ---------------------------------------------------------------------------

#define L 128
#define D 512
#define M 2048
#define TAIL (L - 1)     // 127
#define MAXIT 200
#define EPSV 1e-5f
#define LAM1 0.1f
#define LAM2C 0.1f
#define LD (L * D)       // 65536
#define NBLK 512         // k_loop grid
#define NTHR 512

// workspace offsets (floats)
#define OFF_A     0           // 2 x LD
#define OFF_BM    131072      // 2 x LD
#define OFF_R     262144      // L*M
#define OFF_AX    524288      // L*M
#define OFF_P     786432      // 512x512 (setup GEMM ping) ; k_loop: barrier counters
#define OFF_Q     1048576     // 512x512 (setup GEMM pong) ; k_loop: PART (32x128)
#define OFF_DTD   1310720     // 128x128
#define OFF_DP    1327104     // 128x128
#define OFF_DQ    1343488     // 128x128
#define OFF_CTAB  1359872     // 256
#define OFF_YPREV 1360128     // 128
#define OFF_WV    1362304     // 512 (+WD at +512, WD2 at +640)
#define OFF_VV    1362816     // 512
#define OFF_T64   1363328     // 2048 doubles
#define OFF_Y64   1367424     // 512 doubles
#define OFF_SCAL  1368448     // 64
#define OFF_GRPA  1368512     // setup barrier counters (fence-style)
#define OFF_ROOTA 1369024

#define SC_MX    0
#define SC_MXD   24
#define SC_EIGD  44
#define SC_TAU   45
#define SC_THR   46
#define SI_DONE  48

// k_loop barrier counters live at OFF_P (setup re-zeroes them at its end):
// grp[64] at stride 32 ints (2048), root at +2048, gen at +2064 (2080 total).

__device__ __forceinline__ float delta_elem(int i, int j) {
  if (i == 0) return 0.f;
  if (i == 1) return (j == 0) ? -1.f : (j == 1 ? 1.f : 0.f);
  return (j == i) ? 1.f : (j == i - 1 ? -2.f : (j == i - 2 ? 1.f : 0.f));
}

// ---- device-coherent accessors (relaxed, agent scope -> IC point) ----------
__device__ __forceinline__ float2 ald2(const float* p) {
  unsigned long long v = __hip_atomic_load((const unsigned long long*)p,
                                           __ATOMIC_RELAXED, __HIP_MEMORY_SCOPE_AGENT);
  union { unsigned long long u; float2 f; } cv; cv.u = v; return cv.f;
}
__device__ __forceinline__ float ald1(const float* p) {
  unsigned v = __hip_atomic_load((const unsigned*)p, __ATOMIC_RELAXED,
                                 __HIP_MEMORY_SCOPE_AGENT);
  return __uint_as_float(v);
}
__device__ __forceinline__ void ast1(float* p, float x) {
  __hip_atomic_store((unsigned*)p, __float_as_uint(x), __ATOMIC_RELAXED,
                     __HIP_MEMORY_SCOPE_AGENT);
}

// ---- R4-style fence barrier (k_setup only; proven correct) -----------------
__device__ __forceinline__ void gbarF(float* ws, unsigned ep) {
  __syncthreads();
  if (threadIdx.x == 0) {
    unsigned* grp = (unsigned*)(ws + OFF_GRPA);
    unsigned* root = (unsigned*)(ws + OFF_ROOTA);
    unsigned* gen = root + 16;
    __threadfence();
    unsigned g = (unsigned)blockIdx.x >> 3;  // 32 groups of 8 (256 blocks)
    unsigned a = __hip_atomic_fetch_add(&grp[g * 16], 1u, __ATOMIC_RELAXED,
                                        __HIP_MEMORY_SCOPE_AGENT);
    if (a == ep * 8u + 7u) {
      unsigned r = __hip_atomic_fetch_add(root, 1u, __ATOMIC_RELAXED,
                                          __HIP_MEMORY_SCOPE_AGENT);
      if (r == ep * 32u + 31u)
        __hip_atomic_store(gen, ep + 1u, __ATOMIC_RELAXED, __HIP_MEMORY_SCOPE_AGENT);
    }
    while (__hip_atomic_load(gen, __ATOMIC_RELAXED, __HIP_MEMORY_SCOPE_AGENT) <= ep)
      __builtin_amdgcn_s_sleep(8);
    __threadfence();
  }
  __syncthreads();
}

// ---- fence-free barrier (k_loop): release arrival, relaxed poll ------------
__device__ __forceinline__ void gbar2(unsigned* grp, unsigned ep) {
  __syncthreads();
  if (threadIdx.x == 0) {
    unsigned* root = grp + 2048;
    unsigned* gen = grp + 2064;
    unsigned g = (unsigned)blockIdx.x >> 3;  // 64 groups of 8 (512 blocks)
    unsigned a = __hip_atomic_fetch_add(&grp[g * 32], 1u, __ATOMIC_RELEASE,
                                        __HIP_MEMORY_SCOPE_AGENT);
    if (a == ep * 8u + 7u) {
      unsigned r = __hip_atomic_fetch_add(root, 1u, __ATOMIC_RELEASE,
                                          __HIP_MEMORY_SCOPE_AGENT);
      if (r == ep * 64u + 63u)
        __hip_atomic_store(gen, ep + 1u, __ATOMIC_RELAXED, __HIP_MEMORY_SCOPE_AGENT);
    }
    while (__hip_atomic_load(gen, __ATOMIC_RELAXED, __HIP_MEMORY_SCOPE_AGENT) <= ep)
      __builtin_amdgcn_s_sleep(4);
  }
  asm volatile("" ::: "memory");  // no compiler motion across the barrier
  __syncthreads();
}

// ---------------- init ------------------------------------------------------
__global__ __launch_bounds__(256) void k_init(float* __restrict__ ws,
                                              const float* __restrict__ part_y,
                                              const float* __restrict__ mask,
                                              const float* __restrict__ y0) {
  int gid = blockIdx.x * blockDim.x + threadIdx.x;
  int stride = gridDim.x * blockDim.x;
  for (int i = gid; i < 4 * LD; i += stride) ws[OFF_A + i] = 0.f;
  for (int i = gid; i < L * M; i += stride) ws[OFF_R + i] = -mask[i] * part_y[i];
  for (int i = gid; i < L * L; i += stride) {
    int r = i / L, c = i % L;
    float s = 0.f;
    for (int k = 0; k < L; ++k) s += delta_elem(k, r) * delta_elem(k, c);
    ws[OFF_DTD + i] = s;
  }
  for (int i = gid; i < 1088; i += stride) ((unsigned*)(ws + OFF_GRPA))[i] = 0u;
  if (gid < TAIL) ws[OFF_YPREV + gid] = y0[M + gid];
  if (gid == 0) {
    for (int i = 0; i < 64; ++i) ws[OFF_SCAL + i] = 0.f;  // incl done flag
    ws[OFF_SCAL + SC_MXD] = 6.0f;  // exact max|DtD|
    float a = 1.f;
    for (int t = 0; t < MAXIT; ++t) {
      float an = (1.f + sqrtf(1.f + 4.f * a * a)) * 0.5f;
      ws[OFF_CTAB + t] = (a - 1.f) / an;
      a = an;
    }
  }
}

// ---- one 32x32-tile symmetric-GEMM step: dst = (src/m)^2, track max --------
template <int N, int TILES>
__device__ __forceinline__ void sq_step(const float* __restrict__ src,
                                        float* __restrict__ dst,
                                        float* __restrict__ scal,
                                        int si, int so, float* sm, int bt) {
  float sc = 1.0f / scal[si];
  int r0 = (bt / TILES) * 32, c0 = (bt % TILES) * 32;
  int rr = threadIdx.x >> 5, cl = threadIdx.x & 31;
  int c = c0 + cl;
  const float4* bc = (const float4*)(src + (size_t)c * N);
  const float4* a0p = (const float4*)(src + (size_t)(r0 + rr) * N);
  const float4* a1p = (const float4*)(src + (size_t)(r0 + rr + 16) * N);
  float a0 = 0.f, a1 = 0.f;
  for (int m4 = 0; m4 < N / 4; ++m4) {
    float4 b = bc[m4];
    float4 p = a0p[m4], q = a1p[m4];
    a0 += p.x * b.x + p.y * b.y + p.z * b.z + p.w * b.w;
    a1 += q.x * b.x + q.y * b.y + q.z * b.z + q.w * b.w;
  }
  a0 *= sc * sc; a1 *= sc * sc;
  dst[(size_t)(r0 + rr) * N + c] = a0;
  dst[(size_t)(r0 + rr + 16) * N + c] = a1;
  sm[threadIdx.x] = fmaxf(fabsf(a0), fabsf(a1));
  __syncthreads();
  for (int s = 256; s > 0; s >>= 1) {
    if ((int)threadIdx.x < s) sm[threadIdx.x] = fmaxf(sm[threadIdx.x], sm[threadIdx.x + s]);
    __syncthreads();
  }
  if (threadIdx.x == 0) atomicMax((int*)(scal + so), __float_as_int(sm[0]));
}

// ---------------- setup: spectral norms -> tau/thr (256 blocks) -------------
__global__ __launch_bounds__(NTHR, 2) void k_setup(const float* __restrict__ x,
                                                   float* __restrict__ ws) {
  const int tid = threadIdx.x, bid = blockIdx.x;
  __shared__ float sm[NTHR];
  __shared__ double sdn[NTHR], sdd[NTHR];
  float* scal = ws + OFF_SCAL;
  unsigned ep = 0;

  // S1: P = x x^T (512x512), max -> SC_MX
  {
    int r0 = (bid >> 4) * 32, c0 = (bid & 15) * 32;
    int rr = tid >> 5, cl = tid & 31;
    int c = c0 + cl;
    const float4* xc = (const float4*)(x + (size_t)c * M);
    const float4* xr0 = (const float4*)(x + (size_t)(r0 + rr) * M);
    const float4* xr1 = (const float4*)(x + (size_t)(r0 + rr + 16) * M);
    float a0 = 0.f, a1 = 0.f;
    for (int m4 = 0; m4 < M / 4; ++m4) {
      float4 b = xc[m4];
      float4 p = xr0[m4], q = xr1[m4];
      a0 += p.x * b.x + p.y * b.y + p.z * b.z + p.w * b.w;
      a1 += q.x * b.x + q.y * b.y + q.z * b.z + q.w * b.w;
    }
    float* P = ws + OFF_P;
    P[(size_t)(r0 + rr) * D + c] = a0;
    P[(size_t)(r0 + rr + 16) * D + c] = a1;
    sm[tid] = fmaxf(fabsf(a0), fabsf(a1));
    __syncthreads();
    for (int s = 256; s > 0; s >>= 1) {
      if (tid < s) sm[tid] = fmaxf(sm[tid], sm[tid + s]);
      __syncthreads();
    }
    if (tid == 0) atomicMax((int*)(scal + SC_MX), __float_as_int(sm[0]));
  }
  gbarF(ws, ep++);

  // S2: 12 x-chain squarings; delta chain (10) folded on blocks<16
  for (int s = 0; s < 12; ++s) {
    if (bid < 16 && s < 10) {
      const float* src = (s == 0) ? ws + OFF_DTD : ((s & 1) ? ws + OFF_DP : ws + OFF_DQ);
      float* dst = (s & 1) ? ws + OFF_DQ : ws + OFF_DP;
      sq_step<128, 4>(src, dst, scal, SC_MXD + s, SC_MXD + s + 1, sm, bid);
    }
    __syncthreads();
    {
      const float* src = (s & 1) ? ws + OFF_Q : ws + OFF_P;
      float* dst = (s & 1) ? ws + OFF_P : ws + OFF_Q;
      sq_step<512, 16>(src, dst, scal, SC_MX + s, SC_MX + s + 1, sm, bid);
    }
    gbarF(ws, ep++);
  }
  // x-chain final in P; delta final in dQ

  const float* gP = ws + OFF_P;
  const float* dQ = ws + OFF_DQ;
  // S3a: WV = P*ones (b0); WD = dQ*ones (b1)
  if (bid == 0) {
    const float4* Pr = (const float4*)(gP + (size_t)tid * D);
    float a = 0.f;
    for (int j = 0; j < D / 4; ++j) { float4 v = Pr[j]; a += v.x + v.y + v.z + v.w; }
    ws[OFF_WV + tid] = a;
  }
  if (bid == 1 && tid < L) {
    const float4* Dr = (const float4*)(dQ + (size_t)tid * L);
    float a = 0.f;
    for (int j = 0; j < L / 4; ++j) { float4 v = Dr[j]; a += v.x + v.y + v.z + v.w; }
    ws[OFF_WV + 512 + tid] = a;  // WD
  }
  gbarF(ws, ep++);
  // S3b: VV = P*WV (b0); WD2 = dQ*WD (b1)
  if (bid == 0) {
    const float4* Pr = (const float4*)(gP + (size_t)tid * D);
    const float4* v4 = (const float4*)(ws + OFF_WV);
    float a = 0.f;
    for (int j = 0; j < D / 4; ++j) {
      float4 p = Pr[j]; float4 v = v4[j];
      a += p.x * v.x + p.y * v.y + p.z * v.z + p.w * v.w;
    }
    ws[OFF_VV + tid] = a;
  }
  if (bid == 1 && tid < L) {
    const float* wd = ws + OFF_WV + 512;
    const float* Dr = dQ + (size_t)tid * L;
    float a = 0.f;
    for (int j = 0; j < L; ++j) a += Dr[j] * wd[j];
    ws[OFF_WV + 640 + tid] = a;  // WD2
  }
  gbarF(ws, ep++);
  // S3c: WV = P*VV (b0); eigd Rayleigh on DtD with WD2 (b1)
  if (bid == 0) {
    const float4* Pr = (const float4*)(gP + (size_t)tid * D);
    const float4* v4 = (const float4*)(ws + OFF_VV);
    float a = 0.f;
    for (int j = 0; j < D / 4; ++j) {
      float4 p = Pr[j]; float4 v = v4[j];
      a += p.x * v.x + p.y * v.y + p.z * v.z + p.w * v.w;
    }
    ws[OFF_WV + tid] = a;
  }
  if (bid == 1) {
    float accv = 0.f, vv = 0.f;
    if (tid < L) {
      const float* v = ws + OFF_WV + 640;
      const float* DtD = ws + OFF_DTD;
      for (int j = 0; j < L; ++j) accv += DtD[(size_t)tid * L + j] * v[j];
      vv = v[tid];
    }
    sm[tid] = (tid < L) ? accv * vv : 0.f;
    sm[256 + (tid & 255)] = 0.f;
    __syncthreads();
    if (tid < L) sm[256 + tid] = vv * vv;
    __syncthreads();
    if (tid == 0) {
      float n = 0.f, d = 0.f;
      for (int k = 0; k < L; ++k) { n += sm[k]; d += sm[256 + k]; }
      scal[SC_EIGD] = n / d;
    }
  }
  gbarF(ws, ep++);
  // S3d: VV = P*WV (b0)
  if (bid == 0) {
    const float4* Pr = (const float4*)(gP + (size_t)tid * D);
    const float4* v4 = (const float4*)(ws + OFF_WV);
    float a = 0.f;
    for (int j = 0; j < D / 4; ++j) {
      float4 p = Pr[j]; float4 v = v4[j];
      a += p.x * v.x + p.y * v.y + p.z * v.z + p.w * v.w;
    }
    ws[OFF_VV + tid] = a;
  }
  gbarF(ws, ep++);
  // S4: T64 = x^T * VV (fp64, blocks 0-3)
  if (bid < 4) {
    int m = bid * NTHR + tid;
    double acc = 0.0;
    for (int i = 0; i < D; ++i) acc += (double)x[(size_t)i * M + m] * (double)ws[OFF_VV + i];
    ((double*)(ws + OFF_T64))[m] = acc;
  }
  gbarF(ws, ep++);
  // S5: Y64 = x * T64 (fp64, block 0)
  if (bid == 0) {
    const double* t64 = (const double*)(ws + OFF_T64);
    double acc = 0.0;
    for (int m = 0; m < M; ++m) acc += (double)x[(size_t)tid * M + m] * t64[m];
    ((double*)(ws + OFF_Y64))[tid] = acc;
  }
  gbarF(ws, ep++);
  // S6: tau, thr (block 0)
  if (bid == 0) {
    const double* y = (const double*)(ws + OFF_Y64);
    double vi = (double)ws[OFF_VV + tid];
    sdn[tid] = vi * y[tid];
    sdd[tid] = vi * vi;
    __syncthreads();
    for (int s = 256; s > 0; s >>= 1) {
      if (tid < s) { sdn[tid] += sdn[tid + s]; sdd[tid] += sdd[tid + s]; }
      __syncthreads();
    }
    if (tid == 0) {
      float max_sx = (float)(sdn[0] / sdd[0]);
      float eigD = scal[SC_EIGD];
      float tau = 1.0f / (2.0f * (max_sx + LAM1 * eigD));
      float lam2 = (tau * LAM2C > 0.1f) ? 0.1f / tau : LAM2C;
      scal[SC_TAU] = tau;
      scal[SC_THR] = tau * lam2;
    }
  }
  // zero k_loop barrier counters at OFF_P (all P-reads are done; kernel-end
  // flush publishes before k_loop starts)
  if (bid >= 4 && bid < 9) {
    int idx = (bid - 4) * NTHR + tid;
    if (idx < 2080) ((unsigned*)(ws + OFF_P))[idx] = 0u;
  }
}

// ---------------- main loop: 200 iters, 2 fence-free barriers each ----------
__global__ __launch_bounds__(NTHR, 4) void k_loop(const float* __restrict__ x,
                                                  const float* __restrict__ py,
                                                  const float* __restrict__ mask,
                                                  float* __restrict__ ws,
                                                  float* __restrict__ out) {
  __shared__ float pA[4][128];
  __shared__ float4 pB[4][4][32];
  __shared__ float tileB[4][128];
  __shared__ float snum[128], sden[128];
  __shared__ int flag;
  const int tid = threadIdx.x, bid = blockIdx.x;
  unsigned* grp = (unsigned*)(ws + OFF_P);
  unsigned* idone = (unsigned*)(ws + OFF_SCAL) + SI_DONE;
  const float tau = ws[OFF_SCAL + SC_TAU];
  const float thr = ws[OFF_SCAL + SC_THR];
  float* PART = ws + OFF_Q;  // 32 slots x 128

  // phase A indices: 512 blocks = 32 rt x 16 ct; tile 4 rows x 32 cols; K quarters
  const int qa = tid >> 7, oi = tid & 127;
  const int ra = (bid >> 4) * 4 + (oi >> 5);
  const int ca = (bid & 15) * 32 + (oi & 31);
  // phase B indices: 32 rt x 16 ct; tile 4 rows x 128 cols; K slices of 128
  const int ks = tid >> 7, rr = (tid >> 5) & 3, cg = tid & 31;
  const int rB = (bid >> 4) * 4 + rr;
  const int cB0 = (bid & 15) * 128 + cg * 4;
  int par = 0;

  for (int t = 0; t < MAXIT; ++t) {
    // ---- conv check (block 0, t>=1): PART(t-1) vs YPREV ----
    if (bid == 0 && t >= 1) {
      if (tid < TAIL) {
        float s = 0.f;
#pragma unroll
        for (int slot = 0; slot < 32; ++slot) s += ald1(PART + slot * 128 + tid);
        float ax = s / (float)(TAIL - tid);
        float yp = ws[OFF_YPREV + tid];
        float d0 = yp - ax;
        snum[tid] = d0 * d0;
        sden[tid] = yp * yp;
        ws[OFF_YPREV + tid] = ax;
      }
      __syncthreads();
      if (tid == 0) {
        float num = 0.f, den = 0.f;
        for (int k = 0; k < TAIL; ++k) { num += snum[k]; den += sden[k]; }
        float conv = sqrtf(num) / sqrtf(den);
        if (conv <= EPSV)
          __hip_atomic_store(idone, 1u, __ATOMIC_RELAXED, __HIP_MEMORY_SCOPE_AGENT);
      }
      __syncthreads();
    }
    // ---- phase A: G = R@x^T + LAM1*(DtD@A), prox, momentum ----
    {
      const float* Rrow = ws + OFF_R + (size_t)ra * M + qa * 512;
      const float4* xrow = (const float4*)(x + (size_t)ca * M) + qa * 128;
      float g = 0.f;
#pragma unroll 4
      for (int i = 0; i < 128; ++i) {
        float4 xv = xrow[i];
        float2 r01 = ald2(Rrow + i * 4);
        float2 r23 = ald2(Rrow + i * 4 + 2);
        g += r01.x * xv.x + r01.y * xv.y + r23.x * xv.z + r23.y * xv.w;
      }
      const float* Aold = ws + OFF_A + (size_t)(t & 1) * LD;
      float gd = 0.f;
#pragma unroll 8
      for (int p = qa * 32; p < qa * 32 + 32; ++p)
        gd += ws[OFF_DTD + ra * L + p] * ald1(Aold + (size_t)p * D + ca);
      pA[qa][oi] = g + LAM1 * gd;
      __syncthreads();
      if (tid < 128) {
        float gg = pA[0][tid] + pA[1][tid] + pA[2][tid] + pA[3][tid];
        int r2 = (bid >> 4) * 4 + (tid >> 5);
        int c2 = (bid & 15) * 32 + (tid & 31);
        size_t off = (size_t)r2 * D + c2;
        float* Abase = ws + OFF_A;
        float aold = ald1(Abase + (size_t)(t & 1) * LD + off);
        float bm = ws[OFF_BM + (size_t)(t & 1) * LD + off];
        float ctv = ws[OFF_CTAB + t];
        float z = bm - tau * gg;
        float az = fabsf(z) - thr;
        float anew = az > 0.f ? copysignf(az, z) : 0.f;
        ast1(Abase + (size_t)((t + 1) & 1) * LD + off, anew);
        ws[OFF_BM + (size_t)((t + 1) & 1) * LD + off] = aold + ctv * (anew - aold);
      }
    }
    gbar2(grp, 2u * (unsigned)t);
    // ---- uniform early exit ----
    if (tid == 0)
      flag = (int)__hip_atomic_load(idone, __ATOMIC_RELAXED, __HIP_MEMORY_SCOPE_AGENT);
    __syncthreads();
    if (flag) { par = t & 1; break; }
    // ---- phase B: AX = A_new@x, R update, hankel-tail partials ----
    {
      const float* Anew = ws + OFF_A + (size_t)((t + 1) & 1) * LD;
      const float* Arow = Anew + (size_t)rB * D;
      float4 acc = {0.f, 0.f, 0.f, 0.f};
#pragma unroll 4
      for (int d4 = 0; d4 < 32; ++d4) {
        int d = ks * 128 + d4 * 4;
        float2 a01 = ald2(Arow + d);
        float2 a23 = ald2(Arow + d + 2);
        float4 x0 = *(const float4*)(x + (size_t)(d + 0) * M + cB0);
        float4 x1 = *(const float4*)(x + (size_t)(d + 1) * M + cB0);
        float4 x2 = *(const float4*)(x + (size_t)(d + 2) * M + cB0);
        float4 x3 = *(const float4*)(x + (size_t)(d + 3) * M + cB0);
        acc.x += a01.x * x0.x + a01.y * x1.x + a23.x * x2.x + a23.y * x3.x;
        acc.y += a01.x * x0.y + a01.y * x1.y + a23.x * x2.y + a23.y * x3.y;
        acc.z += a01.x * x0.z + a01.y * x1.z + a23.x * x2.z + a23.y * x3.z;
        acc.w += a01.x * x0.w + a01.y * x1.w + a23.x * x2.w + a23.y * x3.w;
      }
      pB[ks][rr][cg] = acc;
      __syncthreads();
      // final combine: 512 outputs, 1/thread
      int rF = tid >> 7, cF = tid & 127;
      const float* pcol = (const float*)&pB[0][rF][cF >> 2] + (cF & 3);
      float s = pcol[0] + pcol[4 * 32 * 4] + pcol[2 * 4 * 32 * 4] + pcol[3 * 4 * 32 * 4];
      int rg = (bid >> 4) * 4 + rF;
      size_t o = (size_t)rg * M + (bid & 15) * 128 + cF;
      ast1(ws + OFF_AX + o, s);
      ast1(ws + OFF_R + o, mask[o] * (s - py[o]));
      if ((bid & 15) == 15) {  // hankel tail tile (cols 1920..2047)
        tileB[rF][cF] = s;
        __syncthreads();
        int rt = bid >> 4;
        if (tid < TAIL) {
          int rlo = max(4 * rt, tid + 1), rhi = 4 * rt + 3;
          float hs = 0.f;
          for (int r = rlo; r <= rhi; ++r) hs += tileB[r - 4 * rt][128 + tid - r];
          ast1(PART + rt * 128 + tid, hs);
        }
      }
    }
    gbar2(grp, 2u * (unsigned)t + 1u);
  }

  // ---- final output copy (AX then A[par]), device-coherent reads ----
  {
    int gid = bid * NTHR + tid;
    if (gid < L * M / 2) {
      float2 v = ald2(ws + OFF_AX + 2 * gid);
      out[2 * gid] = v.x; out[2 * gid + 1] = v.y;
    }
    if (gid < LD / 2) {
      float2 v = ald2(ws + OFF_A + (size_t)par * LD + 2 * gid);
      out[L * M + 2 * gid] = v.x; out[L * M + 2 * gid + 1] = v.y;
    }
  }
}

// ---------------------------------------------------------------------------
extern "C" void kernel_launch(void* const* d_in, const int* in_sizes, int n_in,
                              void* d_out, int out_size, void* d_ws, size_t ws_size,
                              hipStream_t stream) {
  (void)in_sizes; (void)n_in; (void)out_size; (void)ws_size;
  const float* x = (const float*)d_in[0];
  const float* py = (const float*)d_in[1];
  const float* mk = (const float*)d_in[2];
  const float* y0 = (const float*)d_in[3];
  float* out = (float*)d_out;
  float* ws = (float*)d_ws;

  k_init<<<256, 256, 0, stream>>>(ws, py, mk, y0);
  k_setup<<<256, NTHR, 0, stream>>>(x, ws);
  k_loop<<<NBLK, NTHR, 0, stream>>>(x, py, mk, ws, out);
}